// Round 1
// baseline (463.371 us; speedup 1.0000x reference)
//
#include <hip/hip_runtime.h>
#include <hip/hip_bf16.h>

#define Bn   64
#define Tn   2048
#define ENCD 512
#define DECD 1024
#define HIDD 128
#define TT   32
#define NCH  (Tn / TT)     // 64 chunks per batch
#define LROW 520           // bf16 elems per LDS row: 512 + 8 pad (breaks bank conflicts)

typedef __attribute__((ext_vector_type(8))) short bf16x8;
typedef __attribute__((ext_vector_type(4))) float f32x4;

__device__ __forceinline__ unsigned short f2bf(float f) {
    union { float f; unsigned u; } v; v.f = f;
    unsigned r = v.u + 0x7FFFu + ((v.u >> 16) & 1u);   // RNE
    return (unsigned short)(r >> 16);
}
__device__ __forceinline__ float bf2f(unsigned short s) {
    union { unsigned u; float f; } v; v.u = ((unsigned)s) << 16;
    return v.f;
}
__device__ __forceinline__ float tanh_fast(float x) {
    float xa = fminf(fmaxf(x, -10.f), 10.f);
    float e = __expf(2.f * xa);          // v_exp_f32 path
    return (e - 1.f) / (e + 1.f);
}

// ---------------------------------------------------------------------------
// Kernel 1: qb[b][h] = dec[b]·W_w[h] + V_b[h]   and   Vbf = bf16(V_w)
// ---------------------------------------------------------------------------
__global__ __launch_bounds__(128) void prep(
    const float* __restrict__ dec, const float* __restrict__ Ww,
    const float* __restrict__ Vb,  const float* __restrict__ Vw,
    float* __restrict__ qb, unsigned short* __restrict__ Vbf)
{
    int blk = blockIdx.x, tid = threadIdx.x;
    if (blk < Bn) {
        int b = blk, h = tid;                        // 128 threads == HIDD
        const float4* w = (const float4*)(Ww + (size_t)h * DECD);
        const float4* d = (const float4*)(dec + (size_t)b * DECD);
        float acc = Vb[h];
        #pragma unroll 4
        for (int i = 0; i < DECD / 4; ++i) {
            float4 a = d[i], bb = w[i];
            acc += a.x * bb.x + a.y * bb.y + a.z * bb.z + a.w * bb.w;
        }
        qb[b * HIDD + h] = acc;
    } else {
        int c = blk - Bn;                            // 0..63, 1024 elems each
        int base = c * 1024;
        #pragma unroll
        for (int i = 0; i < 8; ++i) {
            int idx = base + i * 128 + tid;
            Vbf[idx] = f2bf(Vw[idx]);
        }
    }
}

// ---------------------------------------------------------------------------
// Kernel 2: fused scores + chunk-local softmax partials + partial context.
// grid = (NCH, Bn), block = 256 (4 waves; wave w owns h in [32w, 32w+32))
// ---------------------------------------------------------------------------
__global__ __launch_bounds__(256) void attn_main(
    const float* __restrict__ enc, const int* __restrict__ mask,
    const float* __restrict__ qb,  const unsigned short* __restrict__ Vbf,
    const float* __restrict__ ww,  const float* __restrict__ wb,
    float* __restrict__ pW, float* __restrict__ mC, float* __restrict__ lC,
    float* __restrict__ ctxP)
{
    __shared__ unsigned short encS[TT * LROW];   // 33280 B, bf16 tile
    __shared__ float sS[TT * HIDD];              // 16384 B
    __shared__ float ergS[TT];
    __shared__ float pS[TT];

    const int chunk = blockIdx.x, b = blockIdx.y;
    const int tid = threadIdx.x;
    const int t0 = chunk * TT;

    // ---- stage enc tile (16384 contiguous floats) -> bf16 LDS, coalesced ----
    const float* encTile = enc + ((size_t)b * Tn + t0) * ENCD;
    #pragma unroll
    for (int it = 0; it < 16; ++it) {
        int f4 = it * 256 + tid;                 // float4 index 0..4095
        float4 v = ((const float4*)encTile)[f4];
        int elem = f4 * 4;
        int t = elem >> 9, e = elem & 511;
        ushort4 u;
        u.x = f2bf(v.x); u.y = f2bf(v.y); u.z = f2bf(v.z); u.w = f2bf(v.w);
        *(ushort4*)&encS[t * LROW + e] = u;
    }
    __syncthreads();

    // ---- MFMA: out[t, h] = enc_tile · V_w^T  (M=32, N=128 split 4 waves, K=512)
    const int wave = tid >> 6, lane = tid & 63;
    const int li = lane & 15, quad = lane >> 4;

    f32x4 acc[2][2];                             // [mt][nt]
    #pragma unroll
    for (int mt = 0; mt < 2; ++mt)
        #pragma unroll
        for (int nt = 0; nt < 2; ++nt)
            acc[mt][nt] = (f32x4){0.f, 0.f, 0.f, 0.f};

    const unsigned short* vrow0 = Vbf + (size_t)(wave * 32 + 0  + li) * ENCD;
    const unsigned short* vrow1 = Vbf + (size_t)(wave * 32 + 16 + li) * ENCD;

    #pragma unroll 4
    for (int ks = 0; ks < 16; ++ks) {
        int k0 = ks * 32 + quad * 8;
        bf16x8 a0 = *(const bf16x8*)&encS[(0  + li) * LROW + k0];
        bf16x8 a1 = *(const bf16x8*)&encS[(16 + li) * LROW + k0];
        bf16x8 b0 = *(const bf16x8*)(vrow0 + k0);
        bf16x8 b1 = *(const bf16x8*)(vrow1 + k0);
        acc[0][0] = __builtin_amdgcn_mfma_f32_16x16x32_bf16(a0, b0, acc[0][0], 0, 0, 0);
        acc[0][1] = __builtin_amdgcn_mfma_f32_16x16x32_bf16(a0, b1, acc[0][1], 0, 0, 0);
        acc[1][0] = __builtin_amdgcn_mfma_f32_16x16x32_bf16(a1, b0, acc[1][0], 0, 0, 0);
        acc[1][1] = __builtin_amdgcn_mfma_f32_16x16x32_bf16(a1, b1, acc[1][1], 0, 0, 0);
    }

    // ---- epilogue: s = tanh(k + qb) * w_w, scatter to sS[t][h] ----
    float qv[2], wv[2];
    #pragma unroll
    for (int nt = 0; nt < 2; ++nt) {
        int h = wave * 32 + nt * 16 + li;
        qv[nt] = qb[b * HIDD + h];
        wv[nt] = ww[h];
    }
    #pragma unroll
    for (int mt = 0; mt < 2; ++mt)
        #pragma unroll
        for (int nt = 0; nt < 2; ++nt)
            #pragma unroll
            for (int r = 0; r < 4; ++r) {
                // C/D layout: row = quad*4 + r, col = li
                float x = acc[mt][nt][r] + qv[nt];
                float s = tanh_fast(x) * wv[nt];
                int t = mt * 16 + quad * 4 + r;
                sS[t * HIDD + wave * 32 + nt * 16 + li] = s;
            }
    __syncthreads();

    // ---- erg[t] = sum_h sS[t][h] + w_b, mask -> ergS ----
    {
        int t = tid >> 3, seg = tid & 7;         // 8 lanes per t-row
        const float* row = &sS[t * HIDD + seg * 16];
        float part = 0.f;
        #pragma unroll
        for (int j = 0; j < 16; ++j) part += row[j];
        part += __shfl_xor(part, 1);
        part += __shfl_xor(part, 2);
        part += __shfl_xor(part, 4);
        if (seg == 0) {
            float e = part + wb[0];
            if (mask[b * Tn + t0 + t] != 0) e = -INFINITY;
            ergS[t] = e;
        }
    }
    __syncthreads();

    // ---- chunk softmax partials (wave 0) ----
    if (wave == 0) {
        float e = (lane < TT) ? ergS[lane] : -INFINITY;
        float m = e;
        #pragma unroll
        for (int off = 32; off >= 1; off >>= 1)
            m = fmaxf(m, __shfl_xor(m, off));
        float p = (e == -INFINITY) ? 0.f : __expf(e - m);
        float l = p;
        #pragma unroll
        for (int off = 32; off >= 1; off >>= 1)
            l += __shfl_xor(l, off);
        if (lane < TT) {
            pS[lane] = p;
            pW[(size_t)b * Tn + t0 + lane] = p;
        }
        if (lane == 0) {
            mC[b * NCH + chunk] = m;
            lC[b * NCH + chunk] = l;
        }
    }
    __syncthreads();

    // ---- partial context from LDS tile: ctx[e] = sum_t p[t]*enc[t][e] ----
    {
        int e0 = tid * 2;
        float c0 = 0.f, c1 = 0.f;
        #pragma unroll 8
        for (int t = 0; t < TT; ++t) {
            float pt = pS[t];                    // broadcast read
            unsigned pk = *(const unsigned*)&encS[t * LROW + e0];
            c0 += pt * bf2f((unsigned short)(pk & 0xffff));
            c1 += pt * bf2f((unsigned short)(pk >> 16));
        }
        float2 cv; cv.x = c0; cv.y = c1;
        *(float2*)&ctxP[((size_t)(b * NCH + chunk)) * ENCD + e0] = cv;
    }
}

// ---------------------------------------------------------------------------
// Kernel 3: combine chunks -> weights + context.  grid = Bn, block = 256
// ---------------------------------------------------------------------------
__global__ __launch_bounds__(256) void finalize(
    const float* __restrict__ mC, const float* __restrict__ lC,
    const float* __restrict__ pW, const float* __restrict__ ctxP,
    float* __restrict__ out)
{
    __shared__ float scaleS[NCH];
    __shared__ float invLs;
    const int b = blockIdx.x, tid = threadIdx.x;
    const int wave = tid >> 6, lane = tid & 63;

    if (wave == 0) {                             // NCH == 64 == wave width
        float m = mC[b * NCH + lane];
        float l = lC[b * NCH + lane];
        float gm = m;
        #pragma unroll
        for (int off = 32; off >= 1; off >>= 1)
            gm = fmaxf(gm, __shfl_xor(gm, off));
        float sc = (m == -INFINITY) ? 0.f : __expf(m - gm);
        float ls = l * sc;
        #pragma unroll
        for (int off = 32; off >= 1; off >>= 1)
            ls += __shfl_xor(ls, off);
        scaleS[lane] = sc;
        if (lane == 0) invLs = 1.f / ls;
    }
    __syncthreads();
    const float invL = invLs;

    // attention weights: out[Bn*ENCD + b*Tn + t]
    float* outw = out + Bn * ENCD;
    for (int t = tid; t < Tn; t += 256)
        outw[(size_t)b * Tn + t] = pW[(size_t)b * Tn + t] * scaleS[t >> 5] * invL;

    // context: out[b*ENCD + e]
    int e0 = tid * 2;
    float c0 = 0.f, c1 = 0.f;
    for (int c = 0; c < NCH; ++c) {
        float sc = scaleS[c];
        float2 v = *(const float2*)&ctxP[((size_t)(b * NCH + c)) * ENCD + e0];
        c0 += sc * v.x;
        c1 += sc * v.y;
    }
    out[b * ENCD + e0]     = c0 * invL;
    out[b * ENCD + e0 + 1] = c1 * invL;
}

// ---------------------------------------------------------------------------
extern "C" void kernel_launch(void* const* d_in, const int* in_sizes, int n_in,
                              void* d_out, int out_size, void* d_ws, size_t ws_size,
                              hipStream_t stream)
{
    const float* enc  = (const float*)d_in[0];
    const float* dec  = (const float*)d_in[1];
    const int*   mask = (const int*)d_in[2];
    const float* Vw   = (const float*)d_in[3];
    const float* Vb   = (const float*)d_in[4];
    const float* Ww   = (const float*)d_in[5];
    const float* ww   = (const float*)d_in[6];
    const float* wb   = (const float*)d_in[7];
    float* out = (float*)d_out;
    float* ws  = (float*)d_ws;

    // ws layout (float offsets):
    float*          qb   = ws;                               //  8192
    unsigned short* Vbf  = (unsigned short*)(ws + 8192);     // 65536 bf16 = 32768 f
    float*          pW   = ws + 40960;                       // 131072
    float*          mC   = ws + 172032;                      //   4096
    float*          lC   = ws + 176128;                      //   4096
    float*          ctxP = ws + 180224;                      // 2097152  (~9.1 MB total)

    hipLaunchKernelGGL(prep, dim3(128), dim3(128), 0, stream, dec, Ww, Vb, Vw, qb, Vbf);
    hipLaunchKernelGGL(attn_main, dim3(NCH, Bn), dim3(256), 0, stream,
                       enc, mask, qb, Vbf, ww, wb, pW, mC, lC, ctxP);
    hipLaunchKernelGGL(finalize, dim3(Bn), dim3(256), 0, stream, mC, lC, pW, ctxP, out);
}

// Round 2
// 390.810 us; speedup vs baseline: 1.1857x; 1.1857x over previous
//
#include <hip/hip_runtime.h>
#include <hip/hip_bf16.h>

#define Bn   64
#define Tn   2048
#define ENCD 512
#define DECD 1024
#define HIDD 128
#define TT   32
#define NCH  (Tn / TT)     // 64 chunks per batch
#define LROW 520           // bf16 elems per LDS row: 512 + 8 pad

typedef __attribute__((ext_vector_type(8))) short bf16x8;
typedef __attribute__((ext_vector_type(4))) float f32x4;

__device__ __forceinline__ unsigned short f2bf(float f) {
    union { float f; unsigned u; } v; v.f = f;
    unsigned r = v.u + 0x7FFFu + ((v.u >> 16) & 1u);   // RNE
    return (unsigned short)(r >> 16);
}
__device__ __forceinline__ float bf2f(unsigned short s) {
    union { unsigned u; float f; } v; v.u = ((unsigned)s) << 16;
    return v.f;
}
__device__ __forceinline__ float tanh_fast(float x) {
    float xa = fminf(fmaxf(x, -10.f), 10.f);
    float e = __expf(2.f * xa);
    return (e - 1.f) / (e + 1.f);
}

// ---------------------------------------------------------------------------
// Kernel 1: qb[b][h] = dec[b]·W_w[h] + V_b[h]   and   Vbf = bf16(V_w)
// grid = 512 (GEMV) + 64 (convert), block = 256
// ---------------------------------------------------------------------------
__global__ __launch_bounds__(256) void prep(
    const float* __restrict__ dec, const float* __restrict__ Ww,
    const float* __restrict__ Vb,  const float* __restrict__ Vw,
    float* __restrict__ qb, unsigned short* __restrict__ Vbf)
{
    const int blk = blockIdx.x, tid = threadIdx.x;
    if (blk < 512) {
        // GEMV: block = (b, hg); 16 h per block, 16 lanes per h
        const int b = blk >> 3, hg = blk & 7;
        const int h_local = tid >> 4, seg = tid & 15;
        const int h = hg * 16 + h_local;
        const float4* w = (const float4*)(Ww + (size_t)h * DECD);
        const float4* d = (const float4*)(dec + (size_t)b * DECD);
        float acc = 0.f;
        #pragma unroll
        for (int j = 0; j < 16; ++j) {
            int f4 = j * 16 + seg;               // coalesced within 16-lane seg
            float4 a = d[f4], bb = w[f4];
            acc += a.x * bb.x + a.y * bb.y + a.z * bb.z + a.w * bb.w;
        }
        acc += __shfl_xor(acc, 1);
        acc += __shfl_xor(acc, 2);
        acc += __shfl_xor(acc, 4);
        acc += __shfl_xor(acc, 8);
        if (seg == 0) qb[b * HIDD + h] = acc + Vb[h];
    } else {
        const int c = blk - 512;                 // 0..63, 512 float4 each
        const float4* src = (const float4*)Vw;
        #pragma unroll
        for (int i = 0; i < 2; ++i) {
            int f4 = c * 512 + tid * 2 + i;
            float4 v = src[f4];
            ushort4 u;
            u.x = f2bf(v.x); u.y = f2bf(v.y); u.z = f2bf(v.z); u.w = f2bf(v.w);
            *(ushort4*)&Vbf[f4 * 4] = u;
        }
    }
}

// ---------------------------------------------------------------------------
// Kernel 2: fused scores + chunk softmax partials + partial context.
// grid = (NCH, Bn), block = 512 (8 waves; wave w owns h in [16w, 16w+16))
// ---------------------------------------------------------------------------
__global__ __launch_bounds__(512, 8) void attn_main(
    const float* __restrict__ enc, const int* __restrict__ mask,
    const float* __restrict__ qb,  const unsigned short* __restrict__ Vbf,
    const float* __restrict__ ww,  const float* __restrict__ wb,
    float* __restrict__ pW, float* __restrict__ mC, float* __restrict__ lC,
    float* __restrict__ ctxP)
{
    __shared__ unsigned short encS[TT * LROW];   // 33280 B
    __shared__ float wpart[8][TT];               // 1024 B
    __shared__ float pS[TT];                     // 128 B

    const int chunk = blockIdx.x, b = blockIdx.y;
    const int tid = threadIdx.x;
    const int t0 = chunk * TT;
    const int wave = tid >> 6, lane = tid & 63;
    const int li = lane & 15, quad = lane >> 4;

    // per-wave h column, early loads (overlap with staging)
    const int h = wave * 16 + li;
    const float qv = qb[b * HIDD + h];
    const float wv = ww[h];

    // ---- stage enc tile (16384 floats) -> bf16 LDS, coalesced ----
    const float* encTile = enc + ((size_t)b * Tn + t0) * ENCD;
    {
        float4 v[8];
        #pragma unroll
        for (int it = 0; it < 8; ++it)
            v[it] = ((const float4*)encTile)[it * 512 + tid];
        #pragma unroll
        for (int it = 0; it < 8; ++it) {
            int f4 = it * 512 + tid;
            int t = f4 >> 7, e = (f4 & 127) * 4;
            ushort4 u;
            u.x = f2bf(v[it].x); u.y = f2bf(v[it].y);
            u.z = f2bf(v[it].z); u.w = f2bf(v[it].w);
            *(ushort4*)&encS[t * LROW + e] = u;
        }
    }
    __syncthreads();

    // ---- MFMA: k[t, h] for this wave's 16 h, all 32 t ----
    f32x4 acc[2];
    acc[0] = (f32x4){0.f, 0.f, 0.f, 0.f};
    acc[1] = (f32x4){0.f, 0.f, 0.f, 0.f};
    const unsigned short* vrow = Vbf + (size_t)h * ENCD;

    #pragma unroll 4
    for (int ks = 0; ks < 16; ++ks) {
        int k0 = ks * 32 + quad * 8;
        bf16x8 a0 = *(const bf16x8*)&encS[(0  + li) * LROW + k0];
        bf16x8 a1 = *(const bf16x8*)&encS[(16 + li) * LROW + k0];
        bf16x8 bb = *(const bf16x8*)(vrow + k0);
        acc[0] = __builtin_amdgcn_mfma_f32_16x16x32_bf16(a0, bb, acc[0], 0, 0, 0);
        acc[1] = __builtin_amdgcn_mfma_f32_16x16x32_bf16(a1, bb, acc[1], 0, 0, 0);
    }

    // ---- epilogue: s = tanh(k + q)*w_w; reduce over the wave's 16 h ----
    #pragma unroll
    for (int mt = 0; mt < 2; ++mt)
        #pragma unroll
        for (int r = 0; r < 4; ++r) {
            float s = tanh_fast(acc[mt][r] + qv) * wv;
            s += __shfl_xor(s, 1);
            s += __shfl_xor(s, 2);
            s += __shfl_xor(s, 4);
            s += __shfl_xor(s, 8);
            if (li == 0) wpart[wave][mt * 16 + quad * 4 + r] = s;
        }
    __syncthreads();

    // ---- wave 0: combine 8 wave partials, chunk softmax ----
    if (wave == 0) {
        float e = -INFINITY;
        if (lane < TT) {
            int t = lane;
            float v = wb[0];
            #pragma unroll
            for (int w = 0; w < 8; ++w) v += wpart[w][t];
            e = (mask[b * Tn + t0 + t] != 0) ? -INFINITY : v;
        }
        float m = e;
        #pragma unroll
        for (int off = 32; off >= 1; off >>= 1)
            m = fmaxf(m, __shfl_xor(m, off));
        float p = (e == -INFINITY) ? 0.f : __expf(e - m);
        float l = p;
        #pragma unroll
        for (int off = 32; off >= 1; off >>= 1)
            l += __shfl_xor(l, off);
        if (lane < TT) {
            pS[lane] = p;
            pW[(size_t)b * Tn + t0 + lane] = p;
        }
        if (lane == 0) {
            mC[b * NCH + chunk] = m;
            lC[b * NCH + chunk] = l;
        }
    }
    __syncthreads();

    // ---- partial context: ctx[e] = sum_t p[t]*enc[t][e], e = tid ----
    {
        float c = 0.f;
        #pragma unroll 8
        for (int t = 0; t < TT; ++t)
            c += pS[t] * bf2f(encS[t * LROW + tid]);
        ctxP[((size_t)(b * NCH + chunk)) * ENCD + tid] = c;
    }
}

// ---------------------------------------------------------------------------
// Kernel 3: combine chunks.  grid = (Bn, 5), block = 256
//   part 0..3: context e-range part*128..+128 ; part 4: weights
// ---------------------------------------------------------------------------
__global__ __launch_bounds__(256) void finalize(
    const float* __restrict__ mC, const float* __restrict__ lC,
    const float* __restrict__ pW, const float* __restrict__ ctxP,
    float* __restrict__ out)
{
    __shared__ float scaleS[NCH];
    __shared__ float invLs;
    __shared__ float red[256];
    const int b = blockIdx.x, part = blockIdx.y, tid = threadIdx.x;
    const int wave = tid >> 6, lane = tid & 63;

    if (wave == 0) {                             // NCH == 64 == wave width
        float m = mC[b * NCH + lane];
        float l = lC[b * NCH + lane];
        float gm = m;
        #pragma unroll
        for (int off = 32; off >= 1; off >>= 1)
            gm = fmaxf(gm, __shfl_xor(gm, off));
        float sc = (m == -INFINITY) ? 0.f : __expf(m - gm);
        float ls = l * sc;
        #pragma unroll
        for (int off = 32; off >= 1; off >>= 1)
            ls += __shfl_xor(ls, off);
        scaleS[lane] = sc;
        if (lane == 0) invLs = 1.f / ls;
    }
    __syncthreads();
    const float invL = invLs;

    if (part < 4) {
        // context: 2 halves of chunks per thread-half, 128 e-cols
        const int e = part * 128 + (tid & 127);
        const int half = tid >> 7;
        float c = 0.f;
        #pragma unroll 8
        for (int cc = half * 32; cc < half * 32 + 32; ++cc)
            c += scaleS[cc] * ctxP[((size_t)(b * NCH + cc)) * ENCD + e];
        red[tid] = c;
        __syncthreads();
        if (tid < 128) {
            int ee = part * 128 + tid;
            out[b * ENCD + ee] = (red[tid] + red[tid + 128]) * invL;
        }
    } else {
        float* outw = out + Bn * ENCD;
        #pragma unroll
        for (int i = 0; i < 8; ++i) {
            int t = i * 256 + tid;
            outw[(size_t)b * Tn + t] = pW[(size_t)b * Tn + t] * scaleS[t >> 5] * invL;
        }
    }
}

// ---------------------------------------------------------------------------
extern "C" void kernel_launch(void* const* d_in, const int* in_sizes, int n_in,
                              void* d_out, int out_size, void* d_ws, size_t ws_size,
                              hipStream_t stream)
{
    const float* enc  = (const float*)d_in[0];
    const float* dec  = (const float*)d_in[1];
    const int*   mask = (const int*)d_in[2];
    const float* Vw   = (const float*)d_in[3];
    const float* Vb   = (const float*)d_in[4];
    const float* Ww   = (const float*)d_in[5];
    const float* ww   = (const float*)d_in[6];
    const float* wb   = (const float*)d_in[7];
    float* out = (float*)d_out;
    float* ws  = (float*)d_ws;

    // ws layout (float offsets):
    float*          qb   = ws;                               //  8192
    unsigned short* Vbf  = (unsigned short*)(ws + 8192);     // 131072 bf16 = 65536 B
    float*          pW   = ws + 40960;                       // 131072
    float*          mC   = ws + 172032;                      //   4096
    float*          lC   = ws + 176128;                      //   4096
    float*          ctxP = ws + 180224;                      // 2097152  (~9.1 MB total)

    hipLaunchKernelGGL(prep, dim3(576), dim3(256), 0, stream, dec, Ww, Vb, Vw, qb, Vbf);
    hipLaunchKernelGGL(attn_main, dim3(NCH, Bn), dim3(512), 0, stream,
                       enc, mask, qb, Vbf, ww, wb, pW, mC, lC, ctxP);
    hipLaunchKernelGGL(finalize, dim3(Bn, 5), dim3(256), 0, stream, mC, lC, pW, ctxP, out);
}